// Round 1
// baseline (489.749 us; speedup 1.0000x reference)
//
#include <hip/hip_runtime.h>

// Problem constants (fixed by the reference):
#define B_ 8
#define S_ 8192
#define D_ 768
#define V_ 64
#define L_ 26

// Tiling for the segment-sum kernel:
#define DSLICE 128          // D columns per block (LDS acc = 64*128*4 = 32 KB -> 4 blocks/CU)
#define DSPLITS 6           // 768 / 128
#define SPLITS 21           // S-chunks; 21*6*8 = 1008 blocks ~= 4/CU * 256 CU capacity
#define NT 256              // 4 waves per block

// Kernel 1: per-(batch, symbol) segment sums over a 128-wide D slice.
// LDS histogram accumulate (ds_add_f32, bank-conflict-free lane%32 pattern),
// then one hardware fp32 global atomic flush per LDS element.
__global__ __launch_bounds__(NT) void seg_sum_kernel(
    const float* __restrict__ h, const int* __restrict__ ids,
    float* __restrict__ gsum, unsigned int* __restrict__ gcnt)
{
    __shared__ float acc[V_ * DSLICE];
    __shared__ unsigned int cnt[V_];

    const int split  = blockIdx.x;
    const int dsplit = blockIdx.y;
    const int b      = blockIdx.z;
    const int tid    = threadIdx.x;
    const int lane   = tid & 63;
    const int wave   = tid >> 6;
    const int d0     = dsplit * DSLICE;

    for (int i = tid; i < V_ * DSLICE; i += NT) acc[i] = 0.f;
    if (tid < V_) cnt[tid] = 0u;
    __syncthreads();

    const int CH  = (S_ + SPLITS - 1) / SPLITS;
    const int s0  = split * CH;
    const int s1  = (s0 + CH < S_) ? (s0 + CH) : S_;
    const int len = s1 - s0;
    const int tw0 = s0 + (len * wave) / 4;       // contiguous quarter per wave
    const int tw1 = s0 + (len * (wave + 1)) / 4;

    const int*   ids_row = ids + b * S_;
    const float* hrow    = h + (size_t)b * S_ * D_ + d0;

    for (int g = tw0; g < tw1; g += 64) {
        const int rem = tw1 - g;
        const int n   = rem < 64 ? rem : 64;
        int sv = (lane < n) ? ids_row[g + lane] : 0;   // coalesced id fetch
        if (dsplit == 0 && lane < n) atomicAdd(&cnt[sv], 1u);
        const float* hbase = hrow + (size_t)g * D_;
        if (n == 64) {
            #pragma unroll 8
            for (int j = 0; j < 64; ++j) {
                const int v = __shfl(sv, j);           // broadcast symbol of token j
                const float x0 = hbase[j * D_ + lane];
                const float x1 = hbase[j * D_ + lane + 64];
                atomicAdd(&acc[v * DSLICE + lane], x0);        // ds_add_f32
                atomicAdd(&acc[v * DSLICE + lane + 64], x1);
            }
        } else {
            for (int j = 0; j < n; ++j) {
                const int v = __shfl(sv, j);
                const float x0 = hbase[j * D_ + lane];
                const float x1 = hbase[j * D_ + lane + 64];
                atomicAdd(&acc[v * DSLICE + lane], x0);
                atomicAdd(&acc[v * DSLICE + lane + 64], x1);
            }
        }
    }
    __syncthreads();

    // Flush LDS -> global accumulators (coalesced, HW fp32 atomics).
    float* gbase = gsum + (size_t)b * V_ * D_ + d0;
    for (int i = tid; i < V_ * DSLICE; i += NT) {
        const int v = i >> 7;             // i / DSLICE
        const int c = i & (DSLICE - 1);   // i % DSLICE
        unsafeAtomicAdd(&gbase[v * D_ + c], acc[i]);
    }
    if (dsplit == 0 && tid < V_) {
        const unsigned int cc = cnt[tid];
        if (cc) atomicAdd(&gcnt[b * V_ + tid], cc);
    }
}

// Kernel 2: mean, classify (26 dot products of length 768), mask, store.
// One wave per (batch, symbol) row.
__global__ __launch_bounds__(64) void finalize_kernel(
    const float* __restrict__ gsum, const unsigned int* __restrict__ gcnt,
    const float* __restrict__ Wm, const float* __restrict__ bias,
    float* __restrict__ out)
{
    const int bv   = blockIdx.x;
    const int v    = bv & (V_ - 1);
    const int lane = threadIdx.x;

    const unsigned int c = gcnt[bv];
    const float inv = 1.f / (float)(c > 1u ? c : 1u);
    const bool present = (c > 0u) && (v > 0);

    float m[12];
    const float* srow = gsum + (size_t)bv * D_;
    #pragma unroll
    for (int j = 0; j < 12; ++j) m[j] = srow[lane + 64 * j] * inv;

    for (int l = 0; l < L_; ++l) {
        const float* wrow = Wm + l * D_;
        float p = 0.f;
        #pragma unroll
        for (int j = 0; j < 12; ++j) p += m[j] * wrow[lane + 64 * j];
        #pragma unroll
        for (int off = 32; off > 0; off >>= 1) p += __shfl_down(p, off);
        if (lane == 0) out[bv * L_ + l] = present ? (p + bias[l]) : 0.f;
    }
}

extern "C" void kernel_launch(void* const* d_in, const int* in_sizes, int n_in,
                              void* d_out, int out_size, void* d_ws, size_t ws_size,
                              hipStream_t stream) {
    // setup_inputs order: hidden_states, W, b, input_ids
    const float* h    = (const float*)d_in[0];
    const float* Wm   = (const float*)d_in[1];
    const float* bias = (const float*)d_in[2];
    const int*   ids  = (const int*)d_in[3];
    float* out = (float*)d_out;

    // Workspace layout: [B*V*D fp32 sums][B*V u32 counts]
    float* gsum = (float*)d_ws;
    unsigned int* gcnt = (unsigned int*)(gsum + (size_t)B_ * V_ * D_);
    const size_t ws_needed = (size_t)B_ * V_ * D_ * sizeof(float)
                           + (size_t)B_ * V_ * sizeof(unsigned int);

    hipMemsetAsync(d_ws, 0, ws_needed, stream);   // ws is re-poisoned each launch

    dim3 grid1(SPLITS, DSPLITS, B_);
    seg_sum_kernel<<<grid1, NT, 0, stream>>>(h, ids, gsum, gcnt);

    finalize_kernel<<<B_ * V_, 64, 0, stream>>>(gsum, gcnt, Wm, bias, out);
}

// Round 2
// 479.372 us; speedup vs baseline: 1.0216x; 1.0216x over previous
//
#include <hip/hip_runtime.h>

// Problem constants (fixed by the reference):
#define B_ 8
#define S_ 8192
#define D_ 768
#define V_ 64
#define L_ 26

// Tiling for the segment-sum kernel:
#define DSLICE 128          // D columns per block (LDS acc = 64*128*4 = 32 KB -> 4 blocks/CU)
#define DSPLITS 6           // 768 / 128
#define SPLITS 21           // S-chunks; 21*6*8 = 1008 blocks ~= 4/CU * 252 CU
#define NT 256              // 4 waves per block

// Kernel 1: per-(batch, symbol) segment sums over a 128-wide D slice.
// LDS histogram accumulate via HARDWARE ds_add_f32 (unsafeAtomicAdd) --
// fire-and-forget, no CAS loop, no dependent LDS round trips.
__global__ __launch_bounds__(NT) void seg_sum_kernel(
    const float* __restrict__ h, const int* __restrict__ ids,
    float* __restrict__ gsum, unsigned int* __restrict__ gcnt)
{
    __shared__ float acc[V_ * DSLICE];
    __shared__ unsigned int cnt[V_];

    const int split  = blockIdx.x;
    const int dsplit = blockIdx.y;
    const int b      = blockIdx.z;
    const int tid    = threadIdx.x;
    const int lane   = tid & 63;
    const int wave   = tid >> 6;
    const int d0     = dsplit * DSLICE;

    for (int i = tid; i < V_ * DSLICE; i += NT) acc[i] = 0.f;
    if (tid < V_) cnt[tid] = 0u;
    __syncthreads();

    const int CH  = (S_ + SPLITS - 1) / SPLITS;
    const int s0  = split * CH;
    const int s1  = (s0 + CH < S_) ? (s0 + CH) : S_;
    const int len = s1 - s0;
    const int tw0 = s0 + (len * wave) / 4;       // contiguous quarter per wave
    const int tw1 = s0 + (len * (wave + 1)) / 4;

    const int*   ids_row = ids + b * S_;
    const float* hrow    = h + (size_t)b * S_ * D_ + d0;

    for (int g = tw0; g < tw1; g += 64) {
        const int rem = tw1 - g;
        const int n   = rem < 64 ? rem : 64;
        int sv = (lane < n) ? ids_row[g + lane] : 0;   // coalesced id fetch
        if (dsplit == 0 && lane < n) atomicAdd(&cnt[sv], 1u);  // native ds_add_u32
        const float* hbase = hrow + (size_t)g * D_;
        if (n == 64) {
            #pragma unroll 8
            for (int j = 0; j < 64; ++j) {
                const int v = __shfl(sv, j);           // broadcast symbol of token j
                const float x0 = hbase[j * D_ + lane];
                const float x1 = hbase[j * D_ + lane + 64];
                unsafeAtomicAdd(&acc[v * DSLICE + lane], x0);       // HW ds_add_f32
                unsafeAtomicAdd(&acc[v * DSLICE + lane + 64], x1);  // HW ds_add_f32
            }
        } else {
            for (int j = 0; j < n; ++j) {
                const int v = __shfl(sv, j);
                const float x0 = hbase[j * D_ + lane];
                const float x1 = hbase[j * D_ + lane + 64];
                unsafeAtomicAdd(&acc[v * DSLICE + lane], x0);
                unsafeAtomicAdd(&acc[v * DSLICE + lane + 64], x1);
            }
        }
    }
    __syncthreads();

    // Flush LDS -> global accumulators (coalesced, HW fp32 global atomics).
    float* gbase = gsum + (size_t)b * V_ * D_ + d0;
    for (int i = tid; i < V_ * DSLICE; i += NT) {
        const int v = i >> 7;             // i / DSLICE
        const int c = i & (DSLICE - 1);   // i % DSLICE
        unsafeAtomicAdd(&gbase[v * D_ + c], acc[i]);
    }
    if (dsplit == 0 && tid < V_) {
        const unsigned int cc = cnt[tid];
        if (cc) atomicAdd(&gcnt[b * V_ + tid], cc);
    }
}

// Kernel 2: mean, classify (26 dot products of length 768), mask, store.
// One block (4 waves) per (batch, symbol) row; waves split the 26 labels.
__global__ __launch_bounds__(256) void finalize_kernel(
    const float* __restrict__ gsum, const unsigned int* __restrict__ gcnt,
    const float* __restrict__ Wm, const float* __restrict__ bias,
    float* __restrict__ out)
{
    const int bv   = blockIdx.x;
    const int v    = bv & (V_ - 1);
    const int lane = threadIdx.x & 63;
    const int wave = threadIdx.x >> 6;

    const unsigned int c = gcnt[bv];
    const float inv = 1.f / (float)(c > 1u ? c : 1u);
    const bool present = (c > 0u) && (v > 0);

    float m[12];
    const float* srow = gsum + (size_t)bv * D_;
    #pragma unroll
    for (int j = 0; j < 12; ++j) m[j] = srow[lane + 64 * j] * inv;

    // wave w handles labels [w*7, min(w*7+7, 26))  -> 7,7,7,5
    const int l0 = wave * 7;
    const int l1 = (l0 + 7 < L_) ? (l0 + 7) : L_;
    for (int l = l0; l < l1; ++l) {
        const float* wrow = Wm + l * D_;
        float p = 0.f;
        #pragma unroll
        for (int j = 0; j < 12; ++j) p += m[j] * wrow[lane + 64 * j];
        #pragma unroll
        for (int off = 32; off > 0; off >>= 1) p += __shfl_down(p, off);
        if (lane == 0) out[bv * L_ + l] = present ? (p + bias[l]) : 0.f;
    }
}

extern "C" void kernel_launch(void* const* d_in, const int* in_sizes, int n_in,
                              void* d_out, int out_size, void* d_ws, size_t ws_size,
                              hipStream_t stream) {
    // setup_inputs order: hidden_states, W, b, input_ids
    const float* h    = (const float*)d_in[0];
    const float* Wm   = (const float*)d_in[1];
    const float* bias = (const float*)d_in[2];
    const int*   ids  = (const int*)d_in[3];
    float* out = (float*)d_out;

    // Workspace layout: [B*V*D fp32 sums][B*V u32 counts]
    float* gsum = (float*)d_ws;
    unsigned int* gcnt = (unsigned int*)(gsum + (size_t)B_ * V_ * D_);
    const size_t ws_needed = (size_t)B_ * V_ * D_ * sizeof(float)
                           + (size_t)B_ * V_ * sizeof(unsigned int);

    hipMemsetAsync(d_ws, 0, ws_needed, stream);   // ws is re-poisoned each launch

    dim3 grid1(SPLITS, DSPLITS, B_);
    seg_sum_kernel<<<grid1, NT, 0, stream>>>(h, ids, gsum, gcnt);

    finalize_kernel<<<B_ * V_, 256, 0, stream>>>(gsum, gcnt, Wm, bias, out);
}

// Round 3
// 313.453 us; speedup vs baseline: 1.5624x; 1.5293x over previous
//
#include <hip/hip_runtime.h>

// Problem constants (fixed by the reference):
#define B_ 8
#define S_ 8192
#define D_ 768
#define V_ 64
#define L_ 26

typedef __attribute__((ext_vector_type(8))) short short8;   // 8 bf16 (4 VGPRs)
typedef __attribute__((ext_vector_type(4))) float floatx4;  // MFMA C/D

#define TOKS 256      // tokens (K) per block
#define NSL  48       // d-columns (N) per wave = 3 tiles of 16

// sums[b] = OneHot(ids[b])^T @ H[b] as bf16 MFMA with exact one-hot A and
// hi/lo-split B (error ~2^-16 relative). No LDS, no per-token chains:
// B-fragments load directly from global (64B-line-exact, each element once).
// grid = (S/TOKS=32, D/(4*NSL)=4, B=8) = 1024 blocks x 256 thr -> 4 blk/CU.
__global__ __launch_bounds__(256) void pool_mfma_kernel(
    const float* __restrict__ h, const int* __restrict__ ids,
    float* __restrict__ gsum)
{
    const int tid  = threadIdx.x;
    const int lane = tid & 63;
    const int wave = tid >> 6;
    const int nl   = lane & 15;   // n (B) / m (A) index within a 16-tile
    const int quad = lane >> 4;   // k-quadrant: lane covers k = quad*8 + j

    const int b  = blockIdx.z;
    const int k0 = blockIdx.x * TOKS;
    const int n0 = blockIdx.y * (4 * NSL) + wave * NSL;

    const int*   idrow = ids + b * S_ + k0;
    const float* hrow  = h + ((size_t)b * S_ + k0) * D_ + n0;

    floatx4 acc[4][3];
    #pragma unroll
    for (int mt = 0; mt < 4; ++mt)
        #pragma unroll
        for (int nt = 0; nt < 3; ++nt) acc[mt][nt] = (floatx4)0.f;

    for (int ks = 0; ks < TOKS; ks += 32) {
        const int kb = ks + quad * 8;
        // this quad's 8 token ids (two aligned int4 loads, L1-broadcast)
        const int4* ip = (const int4*)(idrow + kb);
        const int4 i0 = ip[0], i1 = ip[1];
        const int idv[8] = {i0.x, i0.y, i0.z, i0.w, i1.x, i1.y, i1.z, i1.w};

        // A fragments (one-hot, exact in bf16): A[m=mt*16+nl][k=quad*8+j]
        short8 afrag[4];
        #pragma unroll
        for (int mt = 0; mt < 4; ++mt) {
            const int m = mt * 16 + nl;
            #pragma unroll
            for (int j = 0; j < 8; ++j)
                afrag[mt][j] = (idv[j] == m) ? (short)0x3F80 : (short)0;
        }

        // B fragments per n-tile: B[k=quad*8+j][n=nt*16+nl], hi/lo bf16 split
        #pragma unroll
        for (int nt = 0; nt < 3; ++nt) {
            const float* bp = hrow + (size_t)kb * D_ + nt * 16 + nl;
            float f[8];
            #pragma unroll
            for (int j = 0; j < 8; ++j) f[j] = bp[(size_t)j * D_];
            short8 bhi, blo;
            #pragma unroll
            for (int j = 0; j < 8; ++j) {
                const unsigned u = __builtin_bit_cast(unsigned, f[j]);
                bhi[j] = (short)(u >> 16);
                const float hif = __builtin_bit_cast(float, u & 0xFFFF0000u);
                const float lof = f[j] - hif;
                blo[j] = (short)(__builtin_bit_cast(unsigned, lof) >> 16);
            }
            #pragma unroll
            for (int mt = 0; mt < 4; ++mt) {
                acc[mt][nt] = __builtin_amdgcn_mfma_f32_16x16x32_bf16(
                    afrag[mt], bhi, acc[mt][nt], 0, 0, 0);
                acc[mt][nt] = __builtin_amdgcn_mfma_f32_16x16x32_bf16(
                    afrag[mt], blo, acc[mt][nt], 0, 0, 0);
            }
        }
    }

    // Flush partial sums. C/D layout: col = lane&15, row = quad*4 + reg.
    #pragma unroll
    for (int mt = 0; mt < 4; ++mt)
        #pragma unroll
        for (int nt = 0; nt < 3; ++nt)
            #pragma unroll
            for (int r = 0; r < 4; ++r) {
                const int v = mt * 16 + quad * 4 + r;
                const int d = n0 + nt * 16 + nl;
                unsafeAtomicAdd(&gsum[((size_t)b * V_ + v) * D_ + d],
                                acc[mt][nt][r]);
            }
}

// Histogram of ids -> counts[b][v]. 8 segments per batch, LDS u32 atomics.
__global__ __launch_bounds__(256) void hist_kernel(
    const int* __restrict__ ids, unsigned int* __restrict__ gcnt)
{
    __shared__ unsigned int cnt[V_];
    const int tid = threadIdx.x;
    const int b   = blockIdx.x >> 3;
    const int seg = blockIdx.x & 7;
    if (tid < V_) cnt[tid] = 0u;
    __syncthreads();
    const int per = S_ / 8;  // 1024 ids per segment
    const int4* p = (const int4*)(ids + b * S_ + seg * per);
    for (int i = tid; i < per / 4; i += 256) {
        const int4 q = p[i];
        atomicAdd(&cnt[q.x], 1u); atomicAdd(&cnt[q.y], 1u);
        atomicAdd(&cnt[q.z], 1u); atomicAdd(&cnt[q.w], 1u);
    }
    __syncthreads();
    if (tid < V_ && cnt[tid]) atomicAdd(&gcnt[b * V_ + tid], cnt[tid]);
}

// Mean, classify (26 dots of length 768), mask, store. 4 waves per row.
__global__ __launch_bounds__(256) void finalize_kernel(
    const float* __restrict__ gsum, const unsigned int* __restrict__ gcnt,
    const float* __restrict__ Wm, const float* __restrict__ bias,
    float* __restrict__ out)
{
    const int bv   = blockIdx.x;
    const int v    = bv & (V_ - 1);
    const int lane = threadIdx.x & 63;
    const int wave = threadIdx.x >> 6;

    const unsigned int c = gcnt[bv];
    const float inv = 1.f / (float)(c > 1u ? c : 1u);
    const bool present = (c > 0u) && (v > 0);

    float m[12];
    const float* srow = gsum + (size_t)bv * D_;
    #pragma unroll
    for (int j = 0; j < 12; ++j) m[j] = srow[lane + 64 * j] * inv;

    const int l0 = wave * 7;
    const int l1 = (l0 + 7 < L_) ? (l0 + 7) : L_;
    for (int l = l0; l < l1; ++l) {
        const float* wrow = Wm + l * D_;
        float p = 0.f;
        #pragma unroll
        for (int j = 0; j < 12; ++j) p += m[j] * wrow[lane + 64 * j];
        #pragma unroll
        for (int off = 32; off > 0; off >>= 1) p += __shfl_down(p, off);
        if (lane == 0) out[bv * L_ + l] = present ? (p + bias[l]) : 0.f;
    }
}

extern "C" void kernel_launch(void* const* d_in, const int* in_sizes, int n_in,
                              void* d_out, int out_size, void* d_ws, size_t ws_size,
                              hipStream_t stream) {
    // setup_inputs order: hidden_states, W, b, input_ids
    const float* h    = (const float*)d_in[0];
    const float* Wm   = (const float*)d_in[1];
    const float* bias = (const float*)d_in[2];
    const int*   ids  = (const int*)d_in[3];
    float* out = (float*)d_out;

    // Workspace layout: [B*V*D fp32 sums][B*V u32 counts]
    float* gsum = (float*)d_ws;
    unsigned int* gcnt = (unsigned int*)(gsum + (size_t)B_ * V_ * D_);
    const size_t ws_needed = (size_t)B_ * V_ * D_ * sizeof(float)
                           + (size_t)B_ * V_ * sizeof(unsigned int);

    hipMemsetAsync(d_ws, 0, ws_needed, stream);   // ws is re-poisoned each launch

    hist_kernel<<<B_ * 8, 256, 0, stream>>>(ids, gcnt);

    dim3 grid1(S_ / TOKS, D_ / (4 * NSL), B_);    // (32, 4, 8) = 1024 blocks
    pool_mfma_kernel<<<grid1, 256, 0, stream>>>(h, ids, gsum);

    finalize_kernel<<<B_ * V_, 256, 0, stream>>>(gsum, gcnt, Wm, bias, out);
}

// Round 4
// 297.453 us; speedup vs baseline: 1.6465x; 1.0538x over previous
//
#include <hip/hip_runtime.h>

// Problem constants (fixed by the reference):
#define B_ 8
#define S_ 8192
#define D_ 768
#define V_ 64
#define L_ 26

typedef __attribute__((ext_vector_type(8))) short short8;   // 8 bf16 (4 VGPRs)
typedef __attribute__((ext_vector_type(4))) float floatx4;  // MFMA C/D

#define TOKS 512               // tokens (K) per block
#define SLICES (S_ / TOKS)     // 16 K-slices -> partial-sum planes
#define NSL  48                // d-columns (N) per wave = 3 tiles of 16

// sums[b] = OneHot(ids[b])^T @ H[b] as bf16 MFMA with exact one-hot A and
// hi/lo-split B (error ~2^-16 relative). No LDS staging, no atomics:
// each block writes its partial tile to part[slice][b][v][d] with plain
// stores (ws needs no zero-init). Blocks with blockIdx.y==0 also emit the
// per-slice id histogram. grid = (16, 4, 8) = 512 blocks -> 2 blk/CU.
__global__ __launch_bounds__(256, 2) void pool_mfma_kernel(
    const float* __restrict__ h, const int* __restrict__ ids,
    float* __restrict__ part, unsigned int* __restrict__ cntpart)
{
    __shared__ unsigned int cnt[V_];

    const int tid  = threadIdx.x;
    const int lane = tid & 63;
    const int wave = tid >> 6;
    const int nl   = lane & 15;   // n (B) / m (A) index within a 16-tile
    const int quad = lane >> 4;   // k-quadrant: lane covers k = quad*8 + j

    const int b     = blockIdx.z;
    const int slice = blockIdx.x;
    const int k0    = slice * TOKS;
    const int n0    = blockIdx.y * (4 * NSL) + wave * NSL;

    const int*   idrow = ids + b * S_ + k0;
    const float* hrow  = h + ((size_t)b * S_ + k0) * D_ + n0;

    // Per-slice histogram (only the y==0 plane does it; non-atomic flush).
    if (blockIdx.y == 0) {
        if (tid < V_) cnt[tid] = 0u;
        __syncthreads();
        if (tid < TOKS / 4) {
            const int4 q = ((const int4*)idrow)[tid];
            atomicAdd(&cnt[q.x], 1u); atomicAdd(&cnt[q.y], 1u);
            atomicAdd(&cnt[q.z], 1u); atomicAdd(&cnt[q.w], 1u);
        }
        __syncthreads();
        if (tid < V_) cntpart[(slice * B_ + b) * V_ + tid] = cnt[tid];
    }

    floatx4 acc[4][3];
    #pragma unroll
    for (int mt = 0; mt < 4; ++mt)
        #pragma unroll
        for (int nt = 0; nt < 3; ++nt) acc[mt][nt] = (floatx4)0.f;

    for (int ks = 0; ks < TOKS; ks += 32) {
        const int kb = ks + quad * 8;
        // this quad's 8 token ids (two aligned int4 loads, L1-broadcast)
        const int4* ip = (const int4*)(idrow + kb);
        const int4 i0 = ip[0], i1 = ip[1];
        const int idv[8] = {i0.x, i0.y, i0.z, i0.w, i1.x, i1.y, i1.z, i1.w};

        // A fragments (one-hot, exact in bf16): A[m=mt*16+nl][k=quad*8+j]
        short8 afrag[4];
        #pragma unroll
        for (int mt = 0; mt < 4; ++mt) {
            const int m = mt * 16 + nl;
            #pragma unroll
            for (int j = 0; j < 8; ++j)
                afrag[mt][j] = (idv[j] == m) ? (short)0x3F80 : (short)0;
        }

        // B fragments per n-tile: B[k=quad*8+j][n=nt*16+nl], hi/lo bf16 split
        #pragma unroll
        for (int nt = 0; nt < 3; ++nt) {
            const float* bp = hrow + (size_t)kb * D_ + nt * 16 + nl;
            float f[8];
            #pragma unroll
            for (int j = 0; j < 8; ++j) f[j] = bp[(size_t)j * D_];
            short8 bhi, blo;
            #pragma unroll
            for (int j = 0; j < 8; ++j) {
                const unsigned u = __builtin_bit_cast(unsigned, f[j]);
                bhi[j] = (short)(u >> 16);
                const float hif = __builtin_bit_cast(float, u & 0xFFFF0000u);
                const float lof = f[j] - hif;
                blo[j] = (short)(__builtin_bit_cast(unsigned, lof) >> 16);
            }
            #pragma unroll
            for (int mt = 0; mt < 4; ++mt) {
                acc[mt][nt] = __builtin_amdgcn_mfma_f32_16x16x32_bf16(
                    afrag[mt], bhi, acc[mt][nt], 0, 0, 0);
                acc[mt][nt] = __builtin_amdgcn_mfma_f32_16x16x32_bf16(
                    afrag[mt], blo, acc[mt][nt], 0, 0, 0);
            }
        }
    }

    // Flush partial sums (plain stores). C/D layout: col=lane&15, row=quad*4+r.
    float* pbase = part + ((size_t)(slice * B_ + b) * V_) * D_;
    #pragma unroll
    for (int mt = 0; mt < 4; ++mt)
        #pragma unroll
        for (int nt = 0; nt < 3; ++nt)
            #pragma unroll
            for (int r = 0; r < 4; ++r) {
                const int v = mt * 16 + quad * 4 + r;
                const int d = n0 + nt * 16 + nl;
                pbase[(size_t)v * D_ + d] = acc[mt][nt][r];
            }
}

// Reduce 16 partial planes, mean, classify (26 dots of length 768), mask.
// One block (4 waves) per (batch, symbol) row.
__global__ __launch_bounds__(256) void reduce_finalize_kernel(
    const float* __restrict__ part, const unsigned int* __restrict__ cntpart,
    const float* __restrict__ Wm, const float* __restrict__ bias,
    float* __restrict__ out)
{
    __shared__ float mean[D_];
    __shared__ unsigned int scnt;

    const int tid = threadIdx.x;
    const int bv  = blockIdx.x;
    const int b   = bv >> 6;
    const int v   = bv & (V_ - 1);

    if (tid == 0) scnt = 0u;
    __syncthreads();
    if (tid < SLICES)
        atomicAdd(&scnt, cntpart[(tid * B_ + b) * V_ + v]);

    float s[3];
    #pragma unroll
    for (int j = 0; j < 3; ++j) {
        const int d = tid + j * 256;
        float a = 0.f;
        #pragma unroll
        for (int sl = 0; sl < SLICES; ++sl)
            a += part[((size_t)(sl * B_ + b) * V_ + v) * D_ + d];
        s[j] = a;
    }
    __syncthreads();               // scnt complete
    const unsigned int c = scnt;
    const float inv = 1.f / (float)(c > 1u ? c : 1u);
    #pragma unroll
    for (int j = 0; j < 3; ++j) mean[tid + j * 256] = s[j] * inv;
    __syncthreads();               // means visible

    const bool present = (c > 0u) && (v > 0);
    const int lane = tid & 63;
    const int wave = tid >> 6;
    for (int l = wave; l < L_; l += 4) {
        const float* wrow = Wm + l * D_;
        float p = 0.f;
        #pragma unroll
        for (int j = 0; j < 12; ++j) {
            const int d = lane + 64 * j;
            p += mean[d] * wrow[d];
        }
        #pragma unroll
        for (int off = 32; off > 0; off >>= 1) p += __shfl_down(p, off);
        if (lane == 0) out[bv * L_ + l] = present ? (p + bias[l]) : 0.f;
    }
}

extern "C" void kernel_launch(void* const* d_in, const int* in_sizes, int n_in,
                              void* d_out, int out_size, void* d_ws, size_t ws_size,
                              hipStream_t stream) {
    // setup_inputs order: hidden_states, W, b, input_ids
    const float* h    = (const float*)d_in[0];
    const float* Wm   = (const float*)d_in[1];
    const float* bias = (const float*)d_in[2];
    const int*   ids  = (const int*)d_in[3];
    float* out = (float*)d_out;

    // Workspace: [SLICES][B][V][D] fp32 partial sums, [SLICES][B][V] u32 counts.
    // Every element is written before being read -> no zero-init needed.
    float* part = (float*)d_ws;
    unsigned int* cntpart =
        (unsigned int*)(part + (size_t)SLICES * B_ * V_ * D_);

    dim3 grid1(SLICES, D_ / (4 * NSL), B_);   // (16, 4, 8) = 512 blocks
    pool_mfma_kernel<<<grid1, 256, 0, stream>>>(h, ids, part, cntpart);

    reduce_finalize_kernel<<<B_ * V_, 256, 0, stream>>>(
        part, cntpart, Wm, bias, out);
}